// Round 10
// baseline (49.097 us; speedup 1.0000x reference)
//
#include <hip/hip_runtime.h>
#include <math.h>
#include <stdint.h>

// PedestrianDetector v15 = v14 with ONE variable changed: staging instruction.
//   global_load_lds (direct-to-LDS DMA)  ->  global_load_dwordx4 to VGPR,
//   then ds_write_b128 into the same padded LDS layout.
//
// Rationale (H7): after v14, the probe (6.3 TB/s) and the staged kernel
// (3.35 TB/s) differ only in {load instruction, waves/CU}. v14 proved the
// address pattern, granularity, depth, conflicts, and cache policy are all
// irrelevant; per-CU line service sits at exactly HALF the documented
// ~10B/cy/CU global-load ceiling (m13). Hypothesis: the gload_lds DMA return
// path is the half-rate component under HBM streaming.
//
// This is v10-done-right: v10's spill (103MB scratch) came from lambda-
// captured register arrays; here the staged chunk is four NAMED float4s,
// no lambdas. Validity check in counters: WRITE_SIZE must stay ~1.2MB.
//
// Structure (otherwise v14-verbatim): 256 blocks x 1024 threads, 1 block/CU,
// 64 rows/block, 8 chunks of 256 d. Stage: wave wu owns rows wu*4..wu*4+3;
// one global_load_dwordx4 per row = the row's full 1KB ascending-contiguous
// span (probe-identical). T14 split: loads issued at phase top (hide under
// compute), ds_writes after the post-compute barrier. Padded LDS rows
// (ROWSTR=257) keep reads 2-way-bank-free (v14-verified: 23K conflicts).
// Scalar-W FMA loop, stride-15 reduce, stable top-3 epilogue: verbatim.

#define DCOLS  2048
#define RPB    64               // rows per block
#define NW     16               // waves per block (1024 threads)
#define PSTR   15               // partials row stride (odd -> conflict-free)
#define CCH    256              // chunk width in d (1KB per row per chunk)
#define NCH    (DCOLS / CCH)    // 8 chunks
#define ROWSTR 257              // LDS row stride in floats (+1 -> bank rotate)
#define TILEP  (RPB * ROWSTR)   // 16448 floats per buffer
#define LDSB   (2 * TILEP * 4)  // 131,584 B dynamic

__global__ __launch_bounds__(1024)
void ped_det_kernel_dyn(const float* __restrict__ feat,
                        const float* __restrict__ Wb,   // [2048][12]
                        const float* __restrict__ bb,   // [12]
                        const float* __restrict__ Wc,   // [2048][3]
                        const float* __restrict__ bc,   // [3]
                        float* __restrict__ out,
                        int nrows)
{
    extern __shared__ __align__(16) float lds[];   // [2][TILEP]
    float* P = &lds[0];   // [16][64][15] partials alias (fits in buf0), after loop
    float* S = P;         // [64][16] biased sums alias, behind further barrier

    const int t    = threadIdx.x;
    const int lane = t & 63;
    const int w    = t >> 6;
    const int wu   = __builtin_amdgcn_readfirstlane(w);  // wave-uniform -> scalar W

    const int rowBase = blockIdx.x * RPB;
    const float* fbase = feat + (size_t)rowBase * DCOLS;

    // per-wave staged rows: r0..r0+3; lane i covers bytes [i*16, i*16+16) of
    // each row's 1KB chunk span (ascending contiguous = probe pattern).
    const int r0 = wu * 4;
    const float* g0 = fbase + (size_t)(r0 + 0) * DCOLS + (lane << 2);
    const float* g1 = fbase + (size_t)(r0 + 1) * DCOLS + (lane << 2);
    const float* g2 = fbase + (size_t)(r0 + 2) * DCOLS + (lane << 2);
    const float* g3 = fbase + (size_t)(r0 + 3) * DCOLS + (lane << 2);

    // LDS write offsets (floats): row r -> r*ROWSTR + lane*4
    const int l0 = (r0 + 0) * ROWSTR + (lane << 2);
    const int l1 = (r0 + 1) * ROWSTR + (lane << 2);
    const int l2 = (r0 + 2) * ROWSTR + (lane << 2);
    const int l3 = (r0 + 3) * ROWSTR + (lane << 2);

    float acc[15];
#pragma unroll
    for (int j = 0; j < 15; ++j) acc[j] = 0.0f;

    // ---- prologue: chunk 0 through regs into buf0
    float4 rA = *(const float4*)(g0);
    float4 rB = *(const float4*)(g1);
    float4 rC = *(const float4*)(g2);
    float4 rD = *(const float4*)(g3);
    *(float4*)(&lds[l0]) = rA;
    *(float4*)(&lds[l1]) = rB;
    *(float4*)(&lds[l2]) = rC;
    *(float4*)(&lds[l3]) = rD;
    __syncthreads();

    for (int c = 0; c < NCH; ++c) {
        // issue next chunk's loads early: latency hides under compute(c)
        if (c + 1 < NCH) {
            const int o = (c + 1) * CCH;
            rA = *(const float4*)(g0 + o);
            rB = *(const float4*)(g1 + o);
            rC = *(const float4*)(g2 + o);
            rD = *(const float4*)(g3 + o);
        }

        const float* buf = &lds[(size_t)(c & 1) * TILEP];
        // wave wu consumes content slots s = wu*4+q (wave-uniform d-slice);
        // row = lane. Padded stride: bank = (lane + 4s) & 31 -> 2-way = free.
#pragma unroll
        for (int q = 0; q < 4; ++q) {
            const int s = wu * 4 + q;
            const float4 f = *(const float4*)(buf + (size_t)lane * ROWSTR + s * 4);
            const int du = c * CCH + wu * 16 + q * 4;       // wave-uniform d
            const float* __restrict__ wbp = Wb + (size_t)du * 12;
            const float* __restrict__ wcp = Wc + (size_t)du * 3;
            const float fv[4] = { f.x, f.y, f.z, f.w };
#pragma unroll
            for (int jj = 0; jj < 4; ++jj) {
                const float v = fv[jj];
                acc[0]  += v * wbp[jj * 12 + 0];
                acc[1]  += v * wbp[jj * 12 + 1];
                acc[2]  += v * wbp[jj * 12 + 2];
                acc[3]  += v * wbp[jj * 12 + 3];
                acc[4]  += v * wbp[jj * 12 + 4];
                acc[5]  += v * wbp[jj * 12 + 5];
                acc[6]  += v * wbp[jj * 12 + 6];
                acc[7]  += v * wbp[jj * 12 + 7];
                acc[8]  += v * wbp[jj * 12 + 8];
                acc[9]  += v * wbp[jj * 12 + 9];
                acc[10] += v * wbp[jj * 12 + 10];
                acc[11] += v * wbp[jj * 12 + 11];
                acc[12] += v * wcp[jj * 3 + 0];
                acc[13] += v * wcp[jj * 3 + 1];
                acc[14] += v * wcp[jj * 3 + 2];
            }
        }

        __syncthreads();                 // all waves done reading buf[c&1]
        if (c + 1 < NCH) {
            // write chunk c+1 into the buffer last read at phase c-1 (safe:
            // its readers passed the barrier before phase c began)
            float* nb = &lds[(size_t)((c + 1) & 1) * TILEP];
            *(float4*)(&nb[l0]) = rA;    // compiler inserts the vmcnt waits here
            *(float4*)(&nb[l1]) = rB;
            *(float4*)(&nb[l2]) = rC;
            *(float4*)(&nb[l3]) = rD;
            __syncthreads();             // writes visible before phase c+1 reads
        }
    }

    // ---- reduce + epilogue (v14 verbatim) ----
    {
        float* pp = &P[(wu * RPB + lane) * PSTR];
#pragma unroll
        for (int j = 0; j < 15; ++j) pp[j] = acc[j];
    }
    __syncthreads();

    float sval = 0.0f;
    int rl = 0, jj = 0;
    if (t < RPB * 15) {
        rl = t / 15;
        jj = t % 15;
        float s = 0.0f;
#pragma unroll
        for (int w2 = 0; w2 < NW; ++w2)
            s += P[(w2 * RPB + rl) * PSTR + jj];
        s += (jj < 12) ? bb[jj] : bc[jj - 12];
        sval = s;
    }
    __syncthreads();

    if (t < RPB * 15)
        S[rl * 16 + jj] = sval;
    __syncthreads();

    if (t < RPB) {
        const int r2 = t;
        float box[12];
#pragma unroll
        for (int j = 0; j < 12; ++j) box[j] = S[r2 * 16 + j];
        float conf[3];
#pragma unroll
        for (int a = 0; a < 3; ++a)
            conf[a] = 1.0f / (1.0f + __expf(-S[r2 * 16 + 12 + a]));

        int i0 = 0; float m0 = conf[0];
        if (conf[1] > m0) { i0 = 1; m0 = conf[1]; }
        if (conf[2] > m0) { i0 = 2; m0 = conf[2]; }
        const int ra = (i0 == 0) ? 1 : 0;
        const int rb = (i0 == 2) ? 1 : 2;
        int i1, i2;
        if (conf[rb] > conf[ra]) { i1 = rb; i2 = ra; }
        else                     { i1 = ra; i2 = rb; }
        const int idx[3] = { i0, i1, i2 };

        const int ro = blockIdx.x * RPB + r2;
        float* boxout  = out + (size_t)ro * 12;
        float* confout = out + (size_t)nrows * 12 + (size_t)ro * 3;
        float* valout  = out + (size_t)nrows * 15 + (size_t)ro * 3;
#pragma unroll
        for (int sl = 0; sl < 3; ++sl) {
            const int   a   = idx[sl];
            const float cv  = conf[a];
            const bool  vld = cv > 0.5f;
            float4 bx;
            bx.x = vld ? box[a * 4 + 0] : 0.0f;
            bx.y = vld ? box[a * 4 + 1] : 0.0f;
            bx.z = vld ? box[a * 4 + 2] : 0.0f;
            bx.w = vld ? box[a * 4 + 3] : 0.0f;
            *(float4*)(boxout + sl * 4) = bx;
            confout[sl] = cv;
            valout[sl]  = vld ? 1.0f : 0.0f;
        }
    }
}

extern "C" void kernel_launch(void* const* d_in, const int* in_sizes, int n_in,
                              void* d_out, int out_size, void* d_ws, size_t ws_size,
                              hipStream_t stream) {
    const float* feat = (const float*)d_in[0];
    const float* Wb   = (const float*)d_in[1];
    const float* bb   = (const float*)d_in[2];
    const float* Wc   = (const float*)d_in[3];
    const float* bc   = (const float*)d_in[4];
    float* out = (float*)d_out;

    const int nrows   = in_sizes[0] / DCOLS;   // 16384
    const int nblocks = nrows / RPB;           // 256 -> 1 block/CU

    static int dyn_ok = -1;   // one-time attribute setup (host-side, capture-safe)
    if (dyn_ok < 0) {
        hipError_t e = hipFuncSetAttribute(
            (const void*)ped_det_kernel_dyn,
            hipFuncAttributeMaxDynamicSharedMemorySize, LDSB);
        dyn_ok = (e == hipSuccess) ? 1 : 0;
    }

    ped_det_kernel_dyn<<<dim3(nblocks), dim3(1024), LDSB, stream>>>(
        feat, Wb, bb, Wc, bc, out, nrows);
}